// Round 9
// baseline (2254.474 us; speedup 1.0000x reference)
//
#include <hip/hip_runtime.h>

typedef short bf16x8 __attribute__((ext_vector_type(8)));
typedef float f32x4 __attribute__((ext_vector_type(4)));
typedef unsigned short u16;
typedef unsigned int u32;

#define TOKS 8192
#define DDIM 1024
#define HDIM 2048
#define NEXP 8
#define ROWS_TOTAL (2 * TOKS)

// worklist capacities: m-tiles are 256 rows; sum ceil(count/256) <= 64+8 = 72
#define WL1_CAP 288   // 4 yq per (e,m)
#define WL2_CAP 72

// router sub-counter split: 2048 blocks, sub = blockIdx & 31 -> 64 blocks x 4 tokens
// = 256 tokens per sub; each token adds <=1 entry per expert -> SUBCAP=256 is exact.
#define NSUB 32
#define SUBCAP 256
#define CSTRIDE 32  // ints; 128B per counter line

__device__ __forceinline__ u16 f2b(float f) {
  u32 x;
  __builtin_memcpy(&x, &f, 4);
  return (u16)((x + 0x7fffu + ((x >> 16) & 1u)) >> 16);  // RNE
}

// async global->LDS, 16B per lane. LDS side: wave-uniform base + lane*16.
typedef const __attribute__((address_space(1))) u32* gp_t;
typedef __attribute__((address_space(3))) u32* lp_t;
__device__ __forceinline__ void glds16(const void* g, void* l) {
  __builtin_amdgcn_global_load_lds((gp_t)g, (lp_t)l, 16, 0, 0);
}

// ---------------- weight [K][N] fp32 -> [N][K] bf16 (64x64 LDS transpose) ----------------
// Used for w2 only.
__global__ __launch_bounds__(256) void cvt_wT_kernel(const float* __restrict__ in,
                                                     u16* __restrict__ out, int K, int N) {
  size_t eo = (size_t)blockIdx.z * K * N;
  in += eo; out += eo;
  int n0 = blockIdx.x * 64, k0 = blockIdx.y * 64;
  __shared__ u16 s[64][72];
  int tid = threadIdx.x;
  int kr = tid >> 4, nc = (tid & 15) * 4;
#pragma unroll
  for (int i = 0; i < 4; ++i) {
    int k = k0 + i * 16 + kr;
    float4 v = *(const float4*)(in + (size_t)k * N + n0 + nc);
    ushort4 u;
    u.x = f2b(v.x); u.y = f2b(v.y); u.z = f2b(v.z); u.w = f2b(v.w);
    *(ushort4*)&s[i * 16 + kr][nc] = u;
  }
  __syncthreads();
  int nl = tid >> 2, kc = tid & 3;
  union { int4 v[2]; u16 u[16]; } o;
#pragma unroll
  for (int j = 0; j < 16; ++j) o.u[j] = s[kc * 16 + j][nl];
  u16* op = out + (size_t)(n0 + nl) * K + k0 + kc * 16;
  *(int4*)op = o.v[0];
  *(int4*)(op + 8) = o.v[1];
}

// ---------------- w1/w3 [K][N] fp32 -> interleaved wc [2N][K] bf16 ----------------
// wc row layout: 16-row groups alternate w1^T / w3^T:
//   col j of w{1,3} -> wc row (j>>4)*32 + half*16 + (j&15), half: 0=w1, 1=w3.
// Per-expert out stride = 2*K*N elements.
__global__ __launch_bounds__(256) void cvt_wc_kernel(const float* __restrict__ in,
                                                     u16* __restrict__ out, int K, int N,
                                                     int half) {
  in += (size_t)blockIdx.z * K * N;
  out += (size_t)blockIdx.z * 2 * K * N;
  int n0 = blockIdx.x * 64, k0 = blockIdx.y * 64;
  __shared__ u16 s[64][72];
  int tid = threadIdx.x;
  int kr = tid >> 4, nc = (tid & 15) * 4;
#pragma unroll
  for (int i = 0; i < 4; ++i) {
    int k = k0 + i * 16 + kr;
    float4 v = *(const float4*)(in + (size_t)k * N + n0 + nc);
    ushort4 u;
    u.x = f2b(v.x); u.y = f2b(v.y); u.z = f2b(v.z); u.w = f2b(v.w);
    *(ushort4*)&s[i * 16 + kr][nc] = u;
  }
  __syncthreads();
  int nl = tid >> 2, kc = tid & 3;
  union { int4 v[2]; u16 u[16]; } o;
#pragma unroll
  for (int j = 0; j < 16; ++j) o.u[j] = s[kc * 16 + j][nl];
  int n = n0 + nl;
  int orow = ((n >> 4) << 5) + half * 16 + (n & 15);
  u16* op = out + (size_t)orow * K + k0 + kc * 16;
  *(int4*)op = o.v[0];
  *(int4*)(op + 8) = o.v[1];
}

// ---------------- Router (fused with x->bf16 conversion) ----------------
// One wave per token. float4 x loads; emits xb bf16 in the same pass. Atomic slot
// assignment to 32x8 padded sub-counters (128B apart) -- R5's contention fix.
__global__ __launch_bounds__(256) void router_kernel(
    const float* __restrict__ x, const float* __restrict__ Wg,
    const float* __restrict__ bg, int* __restrict__ counts32,
    int* __restrict__ tok16, float* __restrict__ g16, u16* __restrict__ xb) {
  int lane = threadIdx.x & 63;
  int t = blockIdx.x * 4 + (threadIdx.x >> 6);
  int sub = blockIdx.x & (NSUB - 1);
  const float* xr = x + (size_t)t * DDIM;
  u16* xo = xb + (size_t)t * DDIM;
  float acc[NEXP];
#pragma unroll
  for (int e = 0; e < NEXP; ++e) acc[e] = 0.f;
#pragma unroll
  for (int jj = 0; jj < DDIM / 256; ++jj) {  // 4 iters, 16B/lane
    int d = jj * 256 + lane * 4;
    float4 xv = *(const float4*)(xr + d);
    ushort4 o;
    o.x = f2b(xv.x); o.y = f2b(xv.y); o.z = f2b(xv.z); o.w = f2b(xv.w);
    *(ushort4*)(xo + d) = o;
    float xs[4] = {xv.x, xv.y, xv.z, xv.w};
#pragma unroll
    for (int dd = 0; dd < 4; ++dd) {
      float4 w0 = *(const float4*)(Wg + (d + dd) * NEXP);
      float4 w1v = *(const float4*)(Wg + (d + dd) * NEXP + 4);
      acc[0] += xs[dd] * w0.x; acc[1] += xs[dd] * w0.y;
      acc[2] += xs[dd] * w0.z; acc[3] += xs[dd] * w0.w;
      acc[4] += xs[dd] * w1v.x; acc[5] += xs[dd] * w1v.y;
      acc[6] += xs[dd] * w1v.z; acc[7] += xs[dd] * w1v.w;
    }
  }
#pragma unroll
  for (int off = 32; off > 0; off >>= 1) {
#pragma unroll
    for (int e = 0; e < NEXP; ++e) acc[e] += __shfl_down(acc[e], off, 64);
  }
  if (lane == 0) {
    float v[NEXP];
#pragma unroll
    for (int e = 0; e < NEXP; ++e) v[e] = acc[e] + bg[e];
    int e0 = 0;
    float v0 = v[0];
#pragma unroll
    for (int e = 1; e < NEXP; ++e)
      if (v[e] > v0) { v0 = v[e]; e0 = e; }  // strict >: lowest index wins ties (jax)
    int e1 = -1;
    float v1 = -3.4e38f;
#pragma unroll
    for (int e = 0; e < NEXP; ++e)
      if (e != e0 && v[e] > v1) { v1 = v[e]; e1 = e; }
    if (e1 < 0) e1 = (e0 + 1) & 7;  // NaN hard-guard
    float ex = __expf(v1 - v0);
    float g0 = 1.f / (1.f + ex);
    float g1 = 1.f - g0;
    int c0 = sub * NEXP + e0;
    int s0 = atomicAdd(&counts32[c0 * CSTRIDE], 1);
    if (s0 < SUBCAP) { tok16[c0 * SUBCAP + s0] = t; g16[c0 * SUBCAP + s0] = g0; }
    int c1 = sub * NEXP + e1;
    int s1 = atomicAdd(&counts32[c1 * CSTRIDE], 1);
    if (s1 < SUBCAP) { tok16[c1 * SUBCAP + s1] = t; g16[c1 * SUBCAP + s1] = g1; }
  }
}

// offsets + per-(e,sub) destination bases + compact worklists (m-tile = 256 rows).
__global__ void offsets_kernel(const int* __restrict__ counts32, int* __restrict__ counts,
                               int* __restrict__ offsets, int* __restrict__ dstbase,
                               int* __restrict__ wl1, int* __restrict__ wl2) {
  int t = threadIdx.x;
  __shared__ int sc[NEXP];
  if (t < NEXP) {
    int c[NSUB];
#pragma unroll
    for (int sub = 0; sub < NSUB; ++sub) c[sub] = counts32[(sub * NEXP + t) * CSTRIDE];
    int run = 0;
#pragma unroll
    for (int sub = 0; sub < NSUB; ++sub) { dstbase[sub * NEXP + t] = run; run += c[sub]; }
    counts[t] = run;
    sc[t] = run;
  }
  __syncthreads();
  if (t == 0) {
    int o = 0;
    for (int e = 0; e < NEXP; ++e) { offsets[e] = o; o += sc[e]; }
    int j1 = 0, j2 = 0;
    for (int e = 0; e < NEXP; ++e) {
      int me = (sc[e] + 255) >> 8;
      for (int m = 0; m < me; ++m) {
        if (j1 + 4 <= WL1_CAP) {
#pragma unroll
          for (int yq = 0; yq < 4; ++yq) wl1[1 + j1 + yq] = (e << 8) | (m << 2) | yq;
          j1 += 4;
        }
        if (j2 < WL2_CAP) wl2[1 + j2++] = (e << 8) | m;
      }
    }
    wl1[0] = j1; wl2[0] = j2;
  }
}

// fold per-(sub,e) scratch into contiguous per-expert tok_ids/gates.
// Also records pos[t][2] = the two global row indices of token t (for combine).
__global__ __launch_bounds__(256) void compact_kernel(
    const int* __restrict__ counts32, const int* __restrict__ dstbase,
    const int* __restrict__ offsets,
    const int* __restrict__ tok16, const float* __restrict__ g16,
    int* __restrict__ tok_ids, float* __restrict__ gates,
    int* __restrict__ posc, int* __restrict__ pos) {
  int idx = blockIdx.x;            // sub*NEXP + e
  int e = idx & (NEXP - 1);
  int n = counts32[idx * CSTRIDE];
  if (n > SUBCAP) n = SUBCAP;
  int base = dstbase[idx];
  int eoff = offsets[e];
  for (int i = threadIdx.x; i < n; i += 256) {
    int t = tok16[idx * SUBCAP + i];
    tok_ids[e * TOKS + base + i] = t;
    gates[e * TOKS + base + i]   = g16[idx * SUBCAP + i];
    int slot = atomicAdd(&posc[t], 1);   // 2 per token, zero contention
    if (slot < 2) pos[t * 2 + slot] = eoff + base + i;
  }
}

// out[t] = y2[pos[t][0]] + y2[pos[t][1]]  (gates already applied in ffn2)
__global__ __launch_bounds__(256) void combine_kernel(
    const float* __restrict__ y2, const int* __restrict__ pos,
    float* __restrict__ out) {
  int t = blockIdx.x;
  int r0 = pos[2 * t], r1 = pos[2 * t + 1];
  int c = threadIdx.x * 4;
  float4 a = *(const float4*)(y2 + (size_t)r0 * DDIM + c);
  float4 b = *(const float4*)(y2 + (size_t)r1 * DDIM + c);
  float4 o;
  o.x = a.x + b.x; o.y = a.y + b.y; o.z = a.z + b.z; o.w = a.w + b.w;
  *(float4*)(out + (size_t)t * DDIM + c) = o;
}

// ---------------- Stage A: h = silu(x@w1)*(x@w3) via ONE GEMM over interleaved wc ----
// R8->R9: 256x128 tile, 512 threads, 8 waves (4M x 2N). Per-wave output 64x64
// keeps the 64-reg accumulator (R3 lesson); sync structure stays the proven
// 2-barrier loop (R6 lesson). Staged bytes/FLOP -24%, waves/CU 12->24.
// BK=64, 128B-chunk staging, chunk-XOR swizzle (both-sides involution).
__global__ __launch_bounds__(512, 6) void ffn1_kernel(
    const u16* __restrict__ xb, const u16* __restrict__ wc,
    const int* __restrict__ tok_ids, const int* __restrict__ counts,
    const int* __restrict__ offsets, const int* __restrict__ wl,
    u16* __restrict__ h, int nbase_wc, int hw, int e_arg) {
  int e, m, y;
  if (e_arg >= 0) {  // Mode B: plain grid, y local to chunk
    e = e_arg; m = blockIdx.x; y = blockIdx.y;
    if (m * 256 >= counts[e]) return;
  } else {           // Mode A: worklist decode
    int bid = blockIdx.x;
    int xcd = bid & 7, j = bid >> 3;
    if (j >= wl[0]) return;
    int w = wl[1 + j];
    e = w >> 8; m = (w >> 2) & 63; y = xcd * 4 + (w & 3);
  }
  int count = counts[e];
  int mbase = m * 256;
  int row_off = (e_arg >= 0) ? 0 : offsets[e];
  int n0w = nbase_wc + y * 128;  // wc-row base of this block
  size_t we = (e_arg >= 0) ? 0 : (size_t)e;
  const u16* wce = wc + we * (size_t)(2 * HDIM * DDIM);

  __shared__ u16 sA[256 * 64];   // 32 KB
  __shared__ u16 sB[128 * 64];   // 16 KB
  __shared__ int stok[256];

  int tid = threadIdx.x, lane = tid & 63, wv = tid >> 6;  // wv 0..7
  if (tid < 256) {
    int s = mbase + tid;
    if (s >= count) s = count - 1;
    stok[tid] = tok_ids[e * TOKS + s];
  }
  __syncthreads();

  // staging: 48 segments (32 A rows0..255 + 16 B rows0..127), seg = 8 rows x 128B.
  // wave wv owns segments wv*6..wv*6+5. lane: rloc = lane>>3, chunk = lane&7.
  int rloc = lane >> 3, ch = lane & 7;
  const u16* gsrc[6];
  u16* ldst[6];
#pragma unroll
  for (int i = 0; i < 6; ++i) {
    int s = wv * 6 + i;
    if (s < 32) {
      int r = s * 8 + rloc;              // A row 0..255
      int sw = ch ^ (r & 7);
      gsrc[i] = xb + (size_t)stok[r] * DDIM + sw * 8;
      ldst[i] = sA + s * 512;
    } else {
      int r = (s - 32) * 8 + rloc;       // B row 0..127
      int sw = ch ^ (r & 7);
      gsrc[i] = wce + (size_t)(n0w + r) * DDIM + sw * 8;
      ldst[i] = sB + (s - 32) * 512;
    }
  }

  int wm = wv >> 1, wn = wv & 1;   // 4M x 2N wave grid
  int rsel = lane & 15, q = lane >> 4;

  f32x4 acc[4][4];
#pragma unroll
  for (int i = 0; i < 4; ++i)
#pragma unroll
    for (int j = 0; j < 4; ++j) {
      f32x4 z = {0.f, 0.f, 0.f, 0.f};
      acc[i][j] = z;
    }

  for (int k0 = 0; k0 < DDIM; k0 += 64) {
    __syncthreads();  // prior reads done before overwrite
#pragma unroll
    for (int i = 0; i < 6; ++i) glds16(gsrc[i] + k0, ldst[i]);
    __syncthreads();  // staged data visible

#pragma unroll
    for (int ks = 0; ks < 2; ++ks) {
      bf16x8 aF[4], bF[4];
#pragma unroll
      for (int mi = 0; mi < 4; ++mi) {
        int r = wm * 64 + mi * 16 + rsel;          // 0..255
        int p = (ks * 4 + q) ^ (r & 7);
        aF[mi] = *(const bf16x8*)&sA[r * 64 + p * 8];
      }
#pragma unroll
      for (int ni = 0; ni < 4; ++ni) {
        int r = wn * 64 + ni * 16 + rsel;          // 0..127
        int p = (ks * 4 + q) ^ (r & 7);
        bF[ni] = *(const bf16x8*)&sB[r * 64 + p * 8];
      }
#pragma unroll
      for (int mi = 0; mi < 4; ++mi)
#pragma unroll
        for (int ni = 0; ni < 4; ++ni)
          acc[mi][ni] = __builtin_amdgcn_mfma_f32_16x16x32_bf16(aF[mi], bF[ni], acc[mi][ni], 0, 0, 0);
    }
  }

  // epilogue: ni pairs (0,1) and (2,3) are (u,v) for the same 16 h-cols.
  // h col (buffer-local) = y*64 + (wn*2 + np)*16 + rsel.
  int cm = count - mbase;
#pragma unroll
  for (int mi = 0; mi < 4; ++mi) {
#pragma unroll
    for (int rr = 0; rr < 4; ++rr) {
      int mrow = wm * 64 + mi * 16 + q * 4 + rr;  // C/D: row = quad*4+reg
      if (mrow < cm) {
#pragma unroll
        for (int np = 0; np < 2; ++np) {
          int hcol = y * 64 + (wn * 2 + np) * 16 + rsel;
          float u = acc[mi][2 * np][rr];
          float vv = acc[mi][2 * np + 1][rr];
          float hv = (u / (1.f + __expf(-u))) * vv;  // silu(u)*v
          h[(size_t)(row_off + mbase + mrow) * hw + hcol] = f2b(hv);
        }
      }
    }
  }
}

// ---------------- Stage B: y2[row] = gate * (h @ w2t^T)  (or atomic into out) ----
// Same 256x128/512-thread retile. Mode A: y = xcd (w2 panel L2-resident per XCD).
__global__ __launch_bounds__(512, 6) void ffn2_kernel(
    const u16* __restrict__ h, const u16* __restrict__ w2t,
    const int* __restrict__ tok_ids, const float* __restrict__ gates,
    const int* __restrict__ counts, const int* __restrict__ offsets,
    const int* __restrict__ wl, float* __restrict__ out,
    float* __restrict__ y2, int kbase, int hw, int e_arg) {
  int e, m, y;
  if (e_arg >= 0) {
    e = e_arg; m = blockIdx.x; y = blockIdx.y;
    if (m * 256 >= counts[e]) return;
  } else {
    int bid = blockIdx.x;
    int xcd = bid & 7, j = bid >> 3;
    if (j >= wl[0]) return;
    int w = wl[1 + j];
    e = w >> 8; m = w & 63; y = xcd;
  }
  int count = counts[e];
  int mbase = m * 256;
  int row_off = (e_arg >= 0) ? 0 : offsets[e];
  int n0 = y * 128;
  size_t we = (e_arg >= 0) ? 0 : (size_t)e;
  const u16* w2e = w2t + we * (size_t)(HDIM * DDIM);

  __shared__ u16 sA[256 * 64];
  __shared__ u16 sB[128 * 64];
  __shared__ int stok[256];
  __shared__ float sg[256];

  int tid = threadIdx.x, lane = tid & 63, wv = tid >> 6;
  if (tid < 256) {
    int s = mbase + tid;
    if (s >= count) s = count - 1;
    stok[tid] = tok_ids[e * TOKS + s];
    sg[tid] = gates[e * TOKS + s];
  }
  __syncthreads();

  int rloc = lane >> 3, ch = lane & 7;
  const u16* gsrc[6];
  u16* ldst[6];
#pragma unroll
  for (int i = 0; i < 6; ++i) {
    int s = wv * 6 + i;
    if (s < 32) {
      int r = s * 8 + rloc;
      int slot = mbase + r;
      if (slot >= count) slot = count - 1;
      int sw = ch ^ (r & 7);
      gsrc[i] = h + (size_t)(row_off + slot) * hw + sw * 8;
      ldst[i] = sA + s * 512;
    } else {
      int r = (s - 32) * 8 + rloc;
      int sw = ch ^ (r & 7);
      gsrc[i] = w2e + (size_t)(n0 + r) * HDIM + kbase + sw * 8;
      ldst[i] = sB + (s - 32) * 512;
    }
  }

  int wm = wv >> 1, wn = wv & 1;
  int rsel = lane & 15, q = lane >> 4;

  f32x4 acc[4][4];
#pragma unroll
  for (int i = 0; i < 4; ++i)
#pragma unroll
    for (int j = 0; j < 4; ++j) {
      f32x4 z = {0.f, 0.f, 0.f, 0.f};
      acc[i][j] = z;
    }

  for (int k0 = 0; k0 < hw; k0 += 64) {
    __syncthreads();
#pragma unroll
    for (int i = 0; i < 6; ++i) glds16(gsrc[i] + k0, ldst[i]);
    __syncthreads();

#pragma unroll
    for (int ks = 0; ks < 2; ++ks) {
      bf16x8 aF[4], bF[4];
#pragma unroll
      for (int mi = 0; mi < 4; ++mi) {
        int r = wm * 64 + mi * 16 + rsel;
        int p = (ks * 4 + q) ^ (r & 7);
        aF[mi] = *(const bf16x8*)&sA[r * 64 + p * 8];
      }
#pragma unroll
      for (int ni = 0; ni < 4; ++ni) {
        int r = wn * 64 + ni * 16 + rsel;
        int p = (ks * 4 + q) ^ (r & 7);
        bF[ni] = *(const bf16x8*)&sB[r * 64 + p * 8];
      }
#pragma unroll
      for (int mi = 0; mi < 4; ++mi)
#pragma unroll
        for (int ni = 0; ni < 4; ++ni)
          acc[mi][ni] = __builtin_amdgcn_mfma_f32_16x16x32_bf16(aF[mi], bF[ni], acc[mi][ni], 0, 0, 0);
    }
  }

  int cm = count - mbase;
#pragma unroll
  for (int mi = 0; mi < 4; ++mi) {
#pragma unroll
    for (int rr = 0; rr < 4; ++rr) {
      int mrow = wm * 64 + mi * 16 + q * 4 + rr;
      if (mrow < cm) {
        float g = sg[mrow];
        if (y2) {
          size_t rbase = (size_t)(row_off + mbase + mrow) * DDIM;
#pragma unroll
          for (int ni = 0; ni < 4; ++ni) {
            int col = n0 + wn * 64 + ni * 16 + rsel;
            y2[rbase + col] = g * acc[mi][ni][rr];   // private row: plain store
          }
        } else {
          int t = stok[mrow];
#pragma unroll
          for (int ni = 0; ni < 4; ++ni) {
            int col = n0 + wn * 64 + ni * 16 + rsel;
            atomicAdd(&out[(size_t)t * DDIM + col], g * acc[mi][ni][rr]);
          }
        }
      }
    }
  }
}

extern "C" void kernel_launch(void* const* d_in, const int* in_sizes, int n_in,
                              void* d_out, int out_size, void* d_ws, size_t ws_size,
                              hipStream_t stream) {
  (void)in_sizes; (void)n_in; (void)out_size;
  const float* x  = (const float*)d_in[0];
  const float* Wg = (const float*)d_in[1];
  const float* bg = (const float*)d_in[2];
  const float* w1 = (const float*)d_in[3];
  const float* w3 = (const float*)d_in[4];
  const float* w2 = (const float*)d_in[5];
  float* out = (float*)d_out;

  char* ws = (char*)d_ws;
  int*   tok_ids  = (int*)ws;                 // 256 KB
  float* gates    = (float*)(ws + 262144);    // 256 KB
  int*   counts   = (int*)(ws + 524288);      // 64 B
  int*   offsets  = (int*)(ws + 524352);      // 64 B
  int*   wl1      = (int*)(ws + 524416);      // <=2 KB
  int*   wl2      = (int*)(ws + 528512);      // <=1 KB
  int*   dstbase  = (int*)(ws + 529536);      // 1 KB
  int*   counts32 = (int*)(ws + 532480);      // 32 KB (256 counters x 128B)
  int*   tok16    = (int*)(ws + 565248);      // 256 KB
  float* g16      = (float*)(ws + 827392);    // 256 KB
  int*   posc     = (int*)(ws + 1089536);     // 32 KB
  int*   pos      = (int*)(ws + 1122304);     // 64 KB (TOKS x 2)
  u16*   xb       = (u16*)(ws + (2 << 20));   // 16.78 MB

  const size_t WEXP  = (size_t)HDIM * DDIM * 2;          // 4 MiB per weight per expert
  const size_t WALL  = 3ull * NEXP * WEXP;               // 100.7 MB (wc 64MB + w2t 32MB)
  const size_t HFULL = (size_t)ROWS_TOTAL * HDIM * 2;    // 67.1 MB
  const size_t Y2SZ  = (size_t)ROWS_TOTAL * DDIM * 4;    // 67.1 MB
  const size_t base  = (2 << 20) + 16777216ull;

  hipMemsetAsync(counts32, 0, NEXP * NSUB * CSTRIDE * 4, stream);
  hipMemsetAsync(posc, 0, TOKS * 4, stream);

  router_kernel<<<TOKS / 4, 256, 0, stream>>>(x, Wg, bg, counts32, tok16, g16, xb);
  offsets_kernel<<<1, 64, 0, stream>>>(counts32, counts, offsets, dstbase, wl1, wl2);
  compact_kernel<<<NSUB * NEXP, 256, 0, stream>>>(counts32, dstbase, offsets, tok16, g16,
                                                  tok_ids, gates, posc, pos);

  if (ws_size >= base + WALL + HFULL + Y2SZ) {
    // Mode A+: wc (64 MB) + w2t (32 MB) + h (67 MB) + y2 (67 MB); scatter-free ffn2
    u16* wcb = (u16*)(ws + base);                        // [NEXP][2*HDIM][DDIM]
    u16* w2t = wcb + (size_t)NEXP * 2 * HDIM * DDIM;     // [NEXP][DDIM][HDIM]
    u16* hb  = w2t + (size_t)NEXP * HDIM * DDIM;
    float* y2 = (float*)(hb + (size_t)ROWS_TOTAL * HDIM);
    cvt_wc_kernel<<<dim3(HDIM / 64, DDIM / 64, NEXP), 256, 0, stream>>>(w1, wcb, DDIM, HDIM, 0);
    cvt_wc_kernel<<<dim3(HDIM / 64, DDIM / 64, NEXP), 256, 0, stream>>>(w3, wcb, DDIM, HDIM, 1);
    cvt_wT_kernel<<<dim3(DDIM / 64, HDIM / 64, NEXP), 256, 0, stream>>>(w2, w2t, HDIM, DDIM);
    ffn1_kernel<<<dim3(8 * WL1_CAP), 512, 0, stream>>>(
        xb, wcb, tok_ids, counts, offsets, wl1, hb, 0, HDIM, -1);
    ffn2_kernel<<<dim3(8 * WL2_CAP), 512, 0, stream>>>(
        hb, w2t, tok_ids, gates, counts, offsets, wl2, out, y2, 0, HDIM, -1);
    combine_kernel<<<TOKS, 256, 0, stream>>>(y2, pos, out);
  } else if (ws_size >= base + WALL + HFULL) {
    // Mode A: atomic ffn2 (no room for y2)
    u16* wcb = (u16*)(ws + base);
    u16* w2t = wcb + (size_t)NEXP * 2 * HDIM * DDIM;
    u16* hb  = w2t + (size_t)NEXP * HDIM * DDIM;
    hipMemsetAsync(out, 0, (size_t)TOKS * DDIM * 4, stream);
    cvt_wc_kernel<<<dim3(HDIM / 64, DDIM / 64, NEXP), 256, 0, stream>>>(w1, wcb, DDIM, HDIM, 0);
    cvt_wc_kernel<<<dim3(HDIM / 64, DDIM / 64, NEXP), 256, 0, stream>>>(w3, wcb, DDIM, HDIM, 1);
    cvt_wT_kernel<<<dim3(DDIM / 64, HDIM / 64, NEXP), 256, 0, stream>>>(w2, w2t, HDIM, DDIM);
    ffn1_kernel<<<dim3(8 * WL1_CAP), 512, 0, stream>>>(
        xb, wcb, tok_ids, counts, offsets, wl1, hb, 0, HDIM, -1);
    ffn2_kernel<<<dim3(8 * WL2_CAP), 512, 0, stream>>>(
        hb, w2t, tok_ids, gates, counts, offsets, wl2, out, nullptr, 0, HDIM, -1);
  } else {
    // Mode B: per-expert wc (8 MB) + w2t (4 MB) + h chunking; atomic ffn2
    int hw = 128;
    const int cand[5] = {2048, 1024, 512, 256, 128};
    for (int i = 0; i < 5; ++i)
      if (base + 3 * WEXP + (size_t)TOKS * cand[i] * 2 <= ws_size) { hw = cand[i]; break; }
    u16* wcb = (u16*)(ws + base);                        // [2*HDIM][DDIM]
    u16* w2t = wcb + (size_t)2 * HDIM * DDIM;
    u16* hb  = w2t + (size_t)HDIM * DDIM;
    hipMemsetAsync(out, 0, (size_t)TOKS * DDIM * 4, stream);
    for (int e = 0; e < NEXP; ++e) {
      cvt_wc_kernel<<<dim3(HDIM / 64, DDIM / 64, 1), 256, 0, stream>>>(
          w1 + (size_t)e * DDIM * HDIM, wcb, DDIM, HDIM, 0);
      cvt_wc_kernel<<<dim3(HDIM / 64, DDIM / 64, 1), 256, 0, stream>>>(
          w3 + (size_t)e * DDIM * HDIM, wcb, DDIM, HDIM, 1);
      cvt_wT_kernel<<<dim3(DDIM / 64, HDIM / 64, 1), 256, 0, stream>>>(
          w2 + (size_t)e * HDIM * DDIM, w2t, HDIM, DDIM);
      for (int nb = 0; nb < HDIM; nb += hw) {
        // ffn1 over wc rows [2*nb, 2*nb + 2*hw), h chunk cols [nb, nb+hw)
        ffn1_kernel<<<dim3(TOKS / 256, hw / 64, 1), 512, 0, stream>>>(
            xb, wcb, tok_ids, counts, offsets, nullptr, hb, 2 * nb, hw, e);
        ffn2_kernel<<<dim3(TOKS / 256, DDIM / 128, 1), 512, 0, stream>>>(
            hb, w2t, tok_ids, gates, counts, offsets, nullptr, out, nullptr, nb, hw, e);
      }
    }
  }
}

// Round 10
// 599.162 us; speedup vs baseline: 3.7627x; 3.7627x over previous
//
#include <hip/hip_runtime.h>

typedef short bf16x8 __attribute__((ext_vector_type(8)));
typedef float f32x4 __attribute__((ext_vector_type(4)));
typedef unsigned short u16;
typedef unsigned int u32;

#define TOKS 8192
#define DDIM 1024
#define HDIM 2048
#define NEXP 8
#define ROWS_TOTAL (2 * TOKS)

// worklist capacities: m-tiles are 256 rows; sum ceil(count/256) <= 64+8 = 72
#define WL1_CAP 288   // 4 yq per (e,m)
#define WL2_CAP 72

// router sub-counter split: 2048 blocks, sub = blockIdx & 31 -> 64 blocks x 4 tokens
// = 256 tokens per sub; each token adds <=1 entry per expert -> SUBCAP=256 is exact.
#define NSUB 32
#define SUBCAP 256
#define CSTRIDE 32  // ints; 128B per counter line

__device__ __forceinline__ u16 f2b(float f) {
  u32 x;
  __builtin_memcpy(&x, &f, 4);
  return (u16)((x + 0x7fffu + ((x >> 16) & 1u)) >> 16);  // RNE
}

// async global->LDS, 16B per lane. LDS side: wave-uniform base + lane*16.
typedef const __attribute__((address_space(1))) u32* gp_t;
typedef __attribute__((address_space(3))) u32* lp_t;
__device__ __forceinline__ void glds16(const void* g, void* l) {
  __builtin_amdgcn_global_load_lds((gp_t)g, (lp_t)l, 16, 0, 0);
}

// ---------------- weight [K][N] fp32 -> [N][K] bf16 (64x64 LDS transpose) ----------------
// Used for w2 only.
__global__ __launch_bounds__(256) void cvt_wT_kernel(const float* __restrict__ in,
                                                     u16* __restrict__ out, int K, int N) {
  size_t eo = (size_t)blockIdx.z * K * N;
  in += eo; out += eo;
  int n0 = blockIdx.x * 64, k0 = blockIdx.y * 64;
  __shared__ u16 s[64][72];
  int tid = threadIdx.x;
  int kr = tid >> 4, nc = (tid & 15) * 4;
#pragma unroll
  for (int i = 0; i < 4; ++i) {
    int k = k0 + i * 16 + kr;
    float4 v = *(const float4*)(in + (size_t)k * N + n0 + nc);
    ushort4 u;
    u.x = f2b(v.x); u.y = f2b(v.y); u.z = f2b(v.z); u.w = f2b(v.w);
    *(ushort4*)&s[i * 16 + kr][nc] = u;
  }
  __syncthreads();
  int nl = tid >> 2, kc = tid & 3;
  union { int4 v[2]; u16 u[16]; } o;
#pragma unroll
  for (int j = 0; j < 16; ++j) o.u[j] = s[kc * 16 + j][nl];
  u16* op = out + (size_t)(n0 + nl) * K + k0 + kc * 16;
  *(int4*)op = o.v[0];
  *(int4*)(op + 8) = o.v[1];
}

// ---------------- w1/w3 [K][N] fp32 -> interleaved wc [2N][K] bf16 ----------------
// wc row layout: 16-row groups alternate w1^T / w3^T:
//   col j of w{1,3} -> wc row (j>>4)*32 + half*16 + (j&15), half: 0=w1, 1=w3.
// Per-expert out stride = 2*K*N elements.
__global__ __launch_bounds__(256) void cvt_wc_kernel(const float* __restrict__ in,
                                                     u16* __restrict__ out, int K, int N,
                                                     int half) {
  in += (size_t)blockIdx.z * K * N;
  out += (size_t)blockIdx.z * 2 * K * N;
  int n0 = blockIdx.x * 64, k0 = blockIdx.y * 64;
  __shared__ u16 s[64][72];
  int tid = threadIdx.x;
  int kr = tid >> 4, nc = (tid & 15) * 4;
#pragma unroll
  for (int i = 0; i < 4; ++i) {
    int k = k0 + i * 16 + kr;
    float4 v = *(const float4*)(in + (size_t)k * N + n0 + nc);
    ushort4 u;
    u.x = f2b(v.x); u.y = f2b(v.y); u.z = f2b(v.z); u.w = f2b(v.w);
    *(ushort4*)&s[i * 16 + kr][nc] = u;
  }
  __syncthreads();
  int nl = tid >> 2, kc = tid & 3;
  union { int4 v[2]; u16 u[16]; } o;
#pragma unroll
  for (int j = 0; j < 16; ++j) o.u[j] = s[kc * 16 + j][nl];
  int n = n0 + nl;
  int orow = ((n >> 4) << 5) + half * 16 + (n & 15);
  u16* op = out + (size_t)orow * K + k0 + kc * 16;
  *(int4*)op = o.v[0];
  *(int4*)(op + 8) = o.v[1];
}

// ---------------- Router (fused with x->bf16 conversion) ----------------
// One wave per token. float4 x loads; emits xb bf16 in the same pass. Atomic slot
// assignment to 32x8 padded sub-counters (128B apart) -- R5's contention fix.
__global__ __launch_bounds__(256) void router_kernel(
    const float* __restrict__ x, const float* __restrict__ Wg,
    const float* __restrict__ bg, int* __restrict__ counts32,
    int* __restrict__ tok16, float* __restrict__ g16, u16* __restrict__ xb) {
  int lane = threadIdx.x & 63;
  int t = blockIdx.x * 4 + (threadIdx.x >> 6);
  int sub = blockIdx.x & (NSUB - 1);
  const float* xr = x + (size_t)t * DDIM;
  u16* xo = xb + (size_t)t * DDIM;
  float acc[NEXP];
#pragma unroll
  for (int e = 0; e < NEXP; ++e) acc[e] = 0.f;
#pragma unroll
  for (int jj = 0; jj < DDIM / 256; ++jj) {  // 4 iters, 16B/lane
    int d = jj * 256 + lane * 4;
    float4 xv = *(const float4*)(xr + d);
    ushort4 o;
    o.x = f2b(xv.x); o.y = f2b(xv.y); o.z = f2b(xv.z); o.w = f2b(xv.w);
    *(ushort4*)(xo + d) = o;
    float xs[4] = {xv.x, xv.y, xv.z, xv.w};
#pragma unroll
    for (int dd = 0; dd < 4; ++dd) {
      float4 w0 = *(const float4*)(Wg + (d + dd) * NEXP);
      float4 w1v = *(const float4*)(Wg + (d + dd) * NEXP + 4);
      acc[0] += xs[dd] * w0.x; acc[1] += xs[dd] * w0.y;
      acc[2] += xs[dd] * w0.z; acc[3] += xs[dd] * w0.w;
      acc[4] += xs[dd] * w1v.x; acc[5] += xs[dd] * w1v.y;
      acc[6] += xs[dd] * w1v.z; acc[7] += xs[dd] * w1v.w;
    }
  }
#pragma unroll
  for (int off = 32; off > 0; off >>= 1) {
#pragma unroll
    for (int e = 0; e < NEXP; ++e) acc[e] += __shfl_down(acc[e], off, 64);
  }
  if (lane == 0) {
    float v[NEXP];
#pragma unroll
    for (int e = 0; e < NEXP; ++e) v[e] = acc[e] + bg[e];
    int e0 = 0;
    float v0 = v[0];
#pragma unroll
    for (int e = 1; e < NEXP; ++e)
      if (v[e] > v0) { v0 = v[e]; e0 = e; }  // strict >: lowest index wins ties (jax)
    int e1 = -1;
    float v1 = -3.4e38f;
#pragma unroll
    for (int e = 0; e < NEXP; ++e)
      if (e != e0 && v[e] > v1) { v1 = v[e]; e1 = e; }
    if (e1 < 0) e1 = (e0 + 1) & 7;  // NaN hard-guard
    float ex = __expf(v1 - v0);
    float g0 = 1.f / (1.f + ex);
    float g1 = 1.f - g0;
    int c0 = sub * NEXP + e0;
    int s0 = atomicAdd(&counts32[c0 * CSTRIDE], 1);
    if (s0 < SUBCAP) { tok16[c0 * SUBCAP + s0] = t; g16[c0 * SUBCAP + s0] = g0; }
    int c1 = sub * NEXP + e1;
    int s1 = atomicAdd(&counts32[c1 * CSTRIDE], 1);
    if (s1 < SUBCAP) { tok16[c1 * SUBCAP + s1] = t; g16[c1 * SUBCAP + s1] = g1; }
  }
}

// offsets + per-(e,sub) destination bases + compact worklists (m-tile = 256 rows).
__global__ void offsets_kernel(const int* __restrict__ counts32, int* __restrict__ counts,
                               int* __restrict__ offsets, int* __restrict__ dstbase,
                               int* __restrict__ wl1, int* __restrict__ wl2) {
  int t = threadIdx.x;
  __shared__ int sc[NEXP];
  if (t < NEXP) {
    int c[NSUB];
#pragma unroll
    for (int sub = 0; sub < NSUB; ++sub) c[sub] = counts32[(sub * NEXP + t) * CSTRIDE];
    int run = 0;
#pragma unroll
    for (int sub = 0; sub < NSUB; ++sub) { dstbase[sub * NEXP + t] = run; run += c[sub]; }
    counts[t] = run;
    sc[t] = run;
  }
  __syncthreads();
  if (t == 0) {
    int o = 0;
    for (int e = 0; e < NEXP; ++e) { offsets[e] = o; o += sc[e]; }
    int j1 = 0, j2 = 0;
    for (int e = 0; e < NEXP; ++e) {
      int me = (sc[e] + 255) >> 8;
      for (int m = 0; m < me; ++m) {
        if (j1 + 4 <= WL1_CAP) {
#pragma unroll
          for (int yq = 0; yq < 4; ++yq) wl1[1 + j1 + yq] = (e << 8) | (m << 2) | yq;
          j1 += 4;
        }
        if (j2 < WL2_CAP) wl2[1 + j2++] = (e << 8) | m;
      }
    }
    wl1[0] = j1; wl2[0] = j2;
  }
}

// fold per-(sub,e) scratch into contiguous per-expert tok_ids/gates.
// Also records pos[t][2] = the two global row indices of token t (for combine).
__global__ __launch_bounds__(256) void compact_kernel(
    const int* __restrict__ counts32, const int* __restrict__ dstbase,
    const int* __restrict__ offsets,
    const int* __restrict__ tok16, const float* __restrict__ g16,
    int* __restrict__ tok_ids, float* __restrict__ gates,
    int* __restrict__ posc, int* __restrict__ pos) {
  int idx = blockIdx.x;            // sub*NEXP + e
  int e = idx & (NEXP - 1);
  int n = counts32[idx * CSTRIDE];
  if (n > SUBCAP) n = SUBCAP;
  int base = dstbase[idx];
  int eoff = offsets[e];
  for (int i = threadIdx.x; i < n; i += 256) {
    int t = tok16[idx * SUBCAP + i];
    tok_ids[e * TOKS + base + i] = t;
    gates[e * TOKS + base + i]   = g16[idx * SUBCAP + i];
    int slot = atomicAdd(&posc[t], 1);   // 2 per token, zero contention
    if (slot < 2) pos[t * 2 + slot] = eoff + base + i;
  }
}

// out[t] = y2[pos[t][0]] + y2[pos[t][1]]  (gates already applied in ffn2)
__global__ __launch_bounds__(256) void combine_kernel(
    const float* __restrict__ y2, const int* __restrict__ pos,
    float* __restrict__ out) {
  int t = blockIdx.x;
  int r0 = pos[2 * t], r1 = pos[2 * t + 1];
  int c = threadIdx.x * 4;
  float4 a = *(const float4*)(y2 + (size_t)r0 * DDIM + c);
  float4 b = *(const float4*)(y2 + (size_t)r1 * DDIM + c);
  float4 o;
  o.x = a.x + b.x; o.y = a.y + b.y; o.z = a.z + b.z; o.w = a.w + b.w;
  *(float4*)(out + (size_t)t * DDIM + c) = o;
}

// ---------------- Stage A: h = silu(x@w1)*(x@w3) via ONE GEMM over interleaved wc ----
// 256x128 tile, 512 threads, 8 waves (4M x 2N), per-wave output 64x64 (64-reg acc).
// REGISTER BUDGET (R9 fix): per-SIMD unified pool = 512 regs (m69). Need ~124
// (64 AGPR acc + ~60 arch). launch_bounds(512,4) -> cap 128: fits, no spill,
// 4 waves/SIMD = 2 blocks/CU = 16 waves/CU. R9's (512,6) capped at 85 -> total
// accumulator spill (VGPR=40, 3.6GB scratch writes, 9x slowdown).
// Staging state kept to 6 x u32 offsets; wave-uniform bases re-selected per K-step.
__global__ __launch_bounds__(512, 4) void ffn1_kernel(
    const u16* __restrict__ xb, const u16* __restrict__ wc,
    const int* __restrict__ tok_ids, const int* __restrict__ counts,
    const int* __restrict__ offsets, const int* __restrict__ wl,
    u16* __restrict__ h, int nbase_wc, int hw, int e_arg) {
  int e, m, y;
  if (e_arg >= 0) {  // Mode B: plain grid, y local to chunk
    e = e_arg; m = blockIdx.x; y = blockIdx.y;
    if (m * 256 >= counts[e]) return;
  } else {           // Mode A: worklist decode
    int bid = blockIdx.x;
    int xcd = bid & 7, j = bid >> 3;
    if (j >= wl[0]) return;
    int w = wl[1 + j];
    e = w >> 8; m = (w >> 2) & 63; y = xcd * 4 + (w & 3);
  }
  int count = counts[e];
  int mbase = m * 256;
  int row_off = (e_arg >= 0) ? 0 : offsets[e];
  int n0w = nbase_wc + y * 128;  // wc-row base of this block
  size_t we = (e_arg >= 0) ? 0 : (size_t)e;
  const u16* wce = wc + we * (size_t)(2 * HDIM * DDIM);

  __shared__ u16 sA[256 * 64];   // 32 KB
  __shared__ u16 sB[128 * 64];   // 16 KB
  __shared__ int stok[256];

  int tid = threadIdx.x, lane = tid & 63, wv = tid >> 6;  // wv 0..7
  if (tid < 256) {
    int s = mbase + tid;
    if (s >= count) s = count - 1;
    stok[tid] = tok_ids[e * TOKS + s];
  }
  __syncthreads();

  // staging: 48 segments (32 A rows0..255 + 16 B rows0..127), seg = 8 rows x 128B.
  // wave wv owns segments wv*6..wv*6+5. lane: rloc = lane>>3, chunk = lane&7.
  int rloc = lane >> 3, ch = lane & 7;
  u32 goff[6];
#pragma unroll
  for (int i = 0; i < 6; ++i) {
    int s = wv * 6 + i;
    if (s < 32) {
      int r = s * 8 + rloc;              // A row 0..255
      int sw = ch ^ (r & 7);
      goff[i] = (u32)stok[r] * DDIM + sw * 8;
    } else {
      int r = (s - 32) * 8 + rloc;       // B row 0..127
      int sw = ch ^ (r & 7);
      goff[i] = (u32)(n0w + r) * DDIM + sw * 8;
    }
  }

  int wm = wv >> 1, wn = wv & 1;   // 4M x 2N wave grid
  int rsel = lane & 15, q = lane >> 4;

  f32x4 acc[4][4];
#pragma unroll
  for (int i = 0; i < 4; ++i)
#pragma unroll
    for (int j = 0; j < 4; ++j) {
      f32x4 z = {0.f, 0.f, 0.f, 0.f};
      acc[i][j] = z;
    }

  for (int k0 = 0; k0 < DDIM; k0 += 64) {
    __syncthreads();  // prior reads done before overwrite
#pragma unroll
    for (int i = 0; i < 6; ++i) {
      int s = wv * 6 + i;
      const u16* gb = (s < 32) ? xb : wce;                       // wave-uniform
      u16* lb = (s < 32) ? (sA + s * 512) : (sB + (s - 32) * 512);
      glds16(gb + goff[i] + k0, lb);
    }
    __syncthreads();  // staged data visible

#pragma unroll
    for (int ks = 0; ks < 2; ++ks) {
      bf16x8 aF[4], bF[4];
#pragma unroll
      for (int mi = 0; mi < 4; ++mi) {
        int r = wm * 64 + mi * 16 + rsel;          // 0..255
        int p = (ks * 4 + q) ^ (r & 7);
        aF[mi] = *(const bf16x8*)&sA[r * 64 + p * 8];
      }
#pragma unroll
      for (int ni = 0; ni < 4; ++ni) {
        int r = wn * 64 + ni * 16 + rsel;          // 0..127
        int p = (ks * 4 + q) ^ (r & 7);
        bF[ni] = *(const bf16x8*)&sB[r * 64 + p * 8];
      }
#pragma unroll
      for (int mi = 0; mi < 4; ++mi)
#pragma unroll
        for (int ni = 0; ni < 4; ++ni)
          acc[mi][ni] = __builtin_amdgcn_mfma_f32_16x16x32_bf16(aF[mi], bF[ni], acc[mi][ni], 0, 0, 0);
    }
  }

  // epilogue: ni pairs (0,1) and (2,3) are (u,v) for the same 16 h-cols.
  // h col (buffer-local) = y*64 + (wn*2 + np)*16 + rsel.
  int cm = count - mbase;
#pragma unroll
  for (int mi = 0; mi < 4; ++mi) {
#pragma unroll
    for (int rr = 0; rr < 4; ++rr) {
      int mrow = wm * 64 + mi * 16 + q * 4 + rr;  // C/D: row = quad*4+reg
      if (mrow < cm) {
#pragma unroll
        for (int np = 0; np < 2; ++np) {
          int hcol = y * 64 + (wn * 2 + np) * 16 + rsel;
          float u = acc[mi][2 * np][rr];
          float vv = acc[mi][2 * np + 1][rr];
          float hv = (u / (1.f + __expf(-u))) * vv;  // silu(u)*v
          h[(size_t)(row_off + mbase + mrow) * hw + hcol] = f2b(hv);
        }
      }
    }
  }
}

// ---------------- Stage B: y2[row] = gate * (h @ w2t^T)  (or atomic into out) ----
// Same 256x128/512-thread retile, same register budgeting.
__global__ __launch_bounds__(512, 4) void ffn2_kernel(
    const u16* __restrict__ h, const u16* __restrict__ w2t,
    const int* __restrict__ tok_ids, const float* __restrict__ gates,
    const int* __restrict__ counts, const int* __restrict__ offsets,
    const int* __restrict__ wl, float* __restrict__ out,
    float* __restrict__ y2, int kbase, int hw, int e_arg) {
  int e, m, y;
  if (e_arg >= 0) {
    e = e_arg; m = blockIdx.x; y = blockIdx.y;
    if (m * 256 >= counts[e]) return;
  } else {
    int bid = blockIdx.x;
    int xcd = bid & 7, j = bid >> 3;
    if (j >= wl[0]) return;
    int w = wl[1 + j];
    e = w >> 8; m = w & 63; y = xcd;
  }
  int count = counts[e];
  int mbase = m * 256;
  int row_off = (e_arg >= 0) ? 0 : offsets[e];
  int n0 = y * 128;
  size_t we = (e_arg >= 0) ? 0 : (size_t)e;
  const u16* w2e = w2t + we * (size_t)(HDIM * DDIM);

  __shared__ u16 sA[256 * 64];
  __shared__ u16 sB[128 * 64];
  __shared__ int stok[256];
  __shared__ float sg[256];

  int tid = threadIdx.x, lane = tid & 63, wv = tid >> 6;
  if (tid < 256) {
    int s = mbase + tid;
    if (s >= count) s = count - 1;
    stok[tid] = tok_ids[e * TOKS + s];
    sg[tid] = gates[e * TOKS + s];
  }
  __syncthreads();

  int rloc = lane >> 3, ch = lane & 7;
  u32 goff[6];
#pragma unroll
  for (int i = 0; i < 6; ++i) {
    int s = wv * 6 + i;
    if (s < 32) {
      int r = s * 8 + rloc;
      int slot = mbase + r;
      if (slot >= count) slot = count - 1;
      int sw = ch ^ (r & 7);
      goff[i] = (u32)(row_off + slot) * hw + sw * 8;
    } else {
      int r = (s - 32) * 8 + rloc;
      int sw = ch ^ (r & 7);
      goff[i] = (u32)(n0 + r) * HDIM + kbase + sw * 8;
    }
  }

  int wm = wv >> 1, wn = wv & 1;
  int rsel = lane & 15, q = lane >> 4;

  f32x4 acc[4][4];
#pragma unroll
  for (int i = 0; i < 4; ++i)
#pragma unroll
    for (int j = 0; j < 4; ++j) {
      f32x4 z = {0.f, 0.f, 0.f, 0.f};
      acc[i][j] = z;
    }

  for (int k0 = 0; k0 < hw; k0 += 64) {
    __syncthreads();
#pragma unroll
    for (int i = 0; i < 6; ++i) {
      int s = wv * 6 + i;
      const u16* gb = (s < 32) ? h : w2e;                        // wave-uniform
      u16* lb = (s < 32) ? (sA + s * 512) : (sB + (s - 32) * 512);
      glds16(gb + goff[i] + k0, lb);
    }
    __syncthreads();

#pragma unroll
    for (int ks = 0; ks < 2; ++ks) {
      bf16x8 aF[4], bF[4];
#pragma unroll
      for (int mi = 0; mi < 4; ++mi) {
        int r = wm * 64 + mi * 16 + rsel;
        int p = (ks * 4 + q) ^ (r & 7);
        aF[mi] = *(const bf16x8*)&sA[r * 64 + p * 8];
      }
#pragma unroll
      for (int ni = 0; ni < 4; ++ni) {
        int r = wn * 64 + ni * 16 + rsel;
        int p = (ks * 4 + q) ^ (r & 7);
        bF[ni] = *(const bf16x8*)&sB[r * 64 + p * 8];
      }
#pragma unroll
      for (int mi = 0; mi < 4; ++mi)
#pragma unroll
        for (int ni = 0; ni < 4; ++ni)
          acc[mi][ni] = __builtin_amdgcn_mfma_f32_16x16x32_bf16(aF[mi], bF[ni], acc[mi][ni], 0, 0, 0);
    }
  }

  int cm = count - mbase;
#pragma unroll
  for (int mi = 0; mi < 4; ++mi) {
#pragma unroll
    for (int rr = 0; rr < 4; ++rr) {
      int mrow = wm * 64 + mi * 16 + q * 4 + rr;
      if (mrow < cm) {
        float g = sg[mrow];
        if (y2) {
          size_t rbase = (size_t)(row_off + mbase + mrow) * DDIM;
#pragma unroll
          for (int ni = 0; ni < 4; ++ni) {
            int col = n0 + wn * 64 + ni * 16 + rsel;
            y2[rbase + col] = g * acc[mi][ni][rr];   // private row: plain store
          }
        } else {
          int t = stok[mrow];
#pragma unroll
          for (int ni = 0; ni < 4; ++ni) {
            int col = n0 + wn * 64 + ni * 16 + rsel;
            atomicAdd(&out[(size_t)t * DDIM + col], g * acc[mi][ni][rr]);
          }
        }
      }
    }
  }
}

extern "C" void kernel_launch(void* const* d_in, const int* in_sizes, int n_in,
                              void* d_out, int out_size, void* d_ws, size_t ws_size,
                              hipStream_t stream) {
  (void)in_sizes; (void)n_in; (void)out_size;
  const float* x  = (const float*)d_in[0];
  const float* Wg = (const float*)d_in[1];
  const float* bg = (const float*)d_in[2];
  const float* w1 = (const float*)d_in[3];
  const float* w3 = (const float*)d_in[4];
  const float* w2 = (const float*)d_in[5];
  float* out = (float*)d_out;

  char* ws = (char*)d_ws;
  int*   tok_ids  = (int*)ws;                 // 256 KB
  float* gates    = (float*)(ws + 262144);    // 256 KB
  int*   counts   = (int*)(ws + 524288);      // 64 B
  int*   offsets  = (int*)(ws + 524352);      // 64 B
  int*   wl1      = (int*)(ws + 524416);      // <=2 KB
  int*   wl2      = (int*)(ws + 528512);      // <=1 KB
  int*   dstbase  = (int*)(ws + 529536);      // 1 KB
  int*   counts32 = (int*)(ws + 532480);      // 32 KB (256 counters x 128B)
  int*   tok16    = (int*)(ws + 565248);      // 256 KB
  float* g16      = (float*)(ws + 827392);    // 256 KB
  int*   posc     = (int*)(ws + 1089536);     // 32 KB
  int*   pos      = (int*)(ws + 1122304);     // 64 KB (TOKS x 2)
  u16*   xb       = (u16*)(ws + (2 << 20));   // 16.78 MB

  const size_t WEXP  = (size_t)HDIM * DDIM * 2;          // 4 MiB per weight per expert
  const size_t WALL  = 3ull * NEXP * WEXP;               // 100.7 MB (wc 64MB + w2t 32MB)
  const size_t HFULL = (size_t)ROWS_TOTAL * HDIM * 2;    // 67.1 MB
  const size_t Y2SZ  = (size_t)ROWS_TOTAL * DDIM * 4;    // 67.1 MB
  const size_t base  = (2 << 20) + 16777216ull;

  hipMemsetAsync(counts32, 0, NEXP * NSUB * CSTRIDE * 4, stream);
  hipMemsetAsync(posc, 0, TOKS * 4, stream);

  router_kernel<<<TOKS / 4, 256, 0, stream>>>(x, Wg, bg, counts32, tok16, g16, xb);
  offsets_kernel<<<1, 64, 0, stream>>>(counts32, counts, offsets, dstbase, wl1, wl2);
  compact_kernel<<<NSUB * NEXP, 256, 0, stream>>>(counts32, dstbase, offsets, tok16, g16,
                                                  tok_ids, gates, posc, pos);

  if (ws_size >= base + WALL + HFULL + Y2SZ) {
    // Mode A+: wc (64 MB) + w2t (32 MB) + h (67 MB) + y2 (67 MB); scatter-free ffn2
    u16* wcb = (u16*)(ws + base);                        // [NEXP][2*HDIM][DDIM]
    u16* w2t = wcb + (size_t)NEXP * 2 * HDIM * DDIM;     // [NEXP][DDIM][HDIM]
    u16* hb  = w2t + (size_t)NEXP * HDIM * DDIM;
    float* y2 = (float*)(hb + (size_t)ROWS_TOTAL * HDIM);
    cvt_wc_kernel<<<dim3(HDIM / 64, DDIM / 64, NEXP), 256, 0, stream>>>(w1, wcb, DDIM, HDIM, 0);
    cvt_wc_kernel<<<dim3(HDIM / 64, DDIM / 64, NEXP), 256, 0, stream>>>(w3, wcb, DDIM, HDIM, 1);
    cvt_wT_kernel<<<dim3(DDIM / 64, HDIM / 64, NEXP), 256, 0, stream>>>(w2, w2t, HDIM, DDIM);
    ffn1_kernel<<<dim3(8 * WL1_CAP), 512, 0, stream>>>(
        xb, wcb, tok_ids, counts, offsets, wl1, hb, 0, HDIM, -1);
    ffn2_kernel<<<dim3(8 * WL2_CAP), 512, 0, stream>>>(
        hb, w2t, tok_ids, gates, counts, offsets, wl2, out, y2, 0, HDIM, -1);
    combine_kernel<<<TOKS, 256, 0, stream>>>(y2, pos, out);
  } else if (ws_size >= base + WALL + HFULL) {
    // Mode A: atomic ffn2 (no room for y2)
    u16* wcb = (u16*)(ws + base);
    u16* w2t = wcb + (size_t)NEXP * 2 * HDIM * DDIM;
    u16* hb  = w2t + (size_t)NEXP * HDIM * DDIM;
    hipMemsetAsync(out, 0, (size_t)TOKS * DDIM * 4, stream);
    cvt_wc_kernel<<<dim3(HDIM / 64, DDIM / 64, NEXP), 256, 0, stream>>>(w1, wcb, DDIM, HDIM, 0);
    cvt_wc_kernel<<<dim3(HDIM / 64, DDIM / 64, NEXP), 256, 0, stream>>>(w3, wcb, DDIM, HDIM, 1);
    cvt_wT_kernel<<<dim3(DDIM / 64, HDIM / 64, NEXP), 256, 0, stream>>>(w2, w2t, HDIM, DDIM);
    ffn1_kernel<<<dim3(8 * WL1_CAP), 512, 0, stream>>>(
        xb, wcb, tok_ids, counts, offsets, wl1, hb, 0, HDIM, -1);
    ffn2_kernel<<<dim3(8 * WL2_CAP), 512, 0, stream>>>(
        hb, w2t, tok_ids, gates, counts, offsets, wl2, out, nullptr, 0, HDIM, -1);
  } else {
    // Mode B: per-expert wc (8 MB) + w2t (4 MB) + h chunking; atomic ffn2
    int hw = 128;
    const int cand[5] = {2048, 1024, 512, 256, 128};
    for (int i = 0; i < 5; ++i)
      if (base + 3 * WEXP + (size_t)TOKS * cand[i] * 2 <= ws_size) { hw = cand[i]; break; }
    u16* wcb = (u16*)(ws + base);                        // [2*HDIM][DDIM]
    u16* w2t = wcb + (size_t)2 * HDIM * DDIM;
    u16* hb  = w2t + (size_t)HDIM * DDIM;
    hipMemsetAsync(out, 0, (size_t)TOKS * DDIM * 4, stream);
    for (int e = 0; e < NEXP; ++e) {
      cvt_wc_kernel<<<dim3(HDIM / 64, DDIM / 64, 1), 256, 0, stream>>>(
          w1 + (size_t)e * DDIM * HDIM, wcb, DDIM, HDIM, 0);
      cvt_wc_kernel<<<dim3(HDIM / 64, DDIM / 64, 1), 256, 0, stream>>>(
          w3 + (size_t)e * DDIM * HDIM, wcb, DDIM, HDIM, 1);
      cvt_wT_kernel<<<dim3(DDIM / 64, HDIM / 64, 1), 256, 0, stream>>>(
          w2 + (size_t)e * HDIM * DDIM, w2t, HDIM, DDIM);
      for (int nb = 0; nb < HDIM; nb += hw) {
        // ffn1 over wc rows [2*nb, 2*nb + 2*hw), h chunk cols [nb, nb+hw)
        ffn1_kernel<<<dim3(TOKS / 256, hw / 64, 1), 512, 0, stream>>>(
            xb, wcb, tok_ids, counts, offsets, nullptr, hb, 2 * nb, hw, e);
        ffn2_kernel<<<dim3(TOKS / 256, DDIM / 128, 1), 512, 0, stream>>>(
            hb, w2t, tok_ids, gates, counts, offsets, nullptr, out, nullptr, nb, hw, e);
      }
    }
  }
}

// Round 11
// 551.070 us; speedup vs baseline: 4.0911x; 1.0873x over previous
//
#include <hip/hip_runtime.h>

typedef short bf16x8 __attribute__((ext_vector_type(8)));
typedef float f32x4 __attribute__((ext_vector_type(4)));
typedef unsigned short u16;
typedef unsigned int u32;

#define TOKS 8192
#define DDIM 1024
#define HDIM 2048
#define NEXP 8
#define ROWS_TOTAL (2 * TOKS)

// worklist capacities (m-tile = 128 rows): sum ceil(count/128) <= 128+8 = 136
#define WL1_CAP 544   // 4 yq per (e,m)
#define WL2_CAP 136

// router sub-counter split: 2048 blocks, sub = blockIdx & 31 -> 64 blocks x 4 tokens
// = 256 tokens per sub; each token adds <=1 entry per expert -> SUBCAP=256 is exact.
#define NSUB 32
#define SUBCAP 256
#define CSTRIDE 32  // ints; 128B per counter line

__device__ __forceinline__ u16 f2b(float f) {
  u32 x;
  __builtin_memcpy(&x, &f, 4);
  return (u16)((x + 0x7fffu + ((x >> 16) & 1u)) >> 16);  // RNE
}

// async global->LDS, 16B per lane. LDS side: wave-uniform base + lane*16.
typedef const __attribute__((address_space(1))) u32* gp_t;
typedef __attribute__((address_space(3))) u32* lp_t;
__device__ __forceinline__ void glds16(const void* g, void* l) {
  __builtin_amdgcn_global_load_lds((gp_t)g, (lp_t)l, 16, 0, 0);
}

// ---------------- weight [K][N] fp32 -> [N][K] bf16 (64x64 LDS transpose) ----------------
// Used for w2 only.
__global__ __launch_bounds__(256) void cvt_wT_kernel(const float* __restrict__ in,
                                                     u16* __restrict__ out, int K, int N) {
  size_t eo = (size_t)blockIdx.z * K * N;
  in += eo; out += eo;
  int n0 = blockIdx.x * 64, k0 = blockIdx.y * 64;
  __shared__ u16 s[64][72];
  int tid = threadIdx.x;
  int kr = tid >> 4, nc = (tid & 15) * 4;
#pragma unroll
  for (int i = 0; i < 4; ++i) {
    int k = k0 + i * 16 + kr;
    float4 v = *(const float4*)(in + (size_t)k * N + n0 + nc);
    ushort4 u;
    u.x = f2b(v.x); u.y = f2b(v.y); u.z = f2b(v.z); u.w = f2b(v.w);
    *(ushort4*)&s[i * 16 + kr][nc] = u;
  }
  __syncthreads();
  int nl = tid >> 2, kc = tid & 3;
  union { int4 v[2]; u16 u[16]; } o;
#pragma unroll
  for (int j = 0; j < 16; ++j) o.u[j] = s[kc * 16 + j][nl];
  u16* op = out + (size_t)(n0 + nl) * K + k0 + kc * 16;
  *(int4*)op = o.v[0];
  *(int4*)(op + 8) = o.v[1];
}

// ---------------- w1/w3 [K][N] fp32 -> interleaved wc [2N][K] bf16 (fused halves) ----
// z = e*2 + half; half 0 = w1, 1 = w3. wc row: col j -> (j>>4)*32 + half*16 + (j&15).
__global__ __launch_bounds__(256) void cvt_wc_kernel(const float* __restrict__ w1,
                                                     const float* __restrict__ w3,
                                                     u16* __restrict__ out, int K, int N) {
  int z = blockIdx.z;
  int e = z >> 1, half = z & 1;
  const float* in = (half ? w3 : w1) + (size_t)e * K * N;
  out += (size_t)e * 2 * K * N;
  int n0 = blockIdx.x * 64, k0 = blockIdx.y * 64;
  __shared__ u16 s[64][72];
  int tid = threadIdx.x;
  int kr = tid >> 4, nc = (tid & 15) * 4;
#pragma unroll
  for (int i = 0; i < 4; ++i) {
    int k = k0 + i * 16 + kr;
    float4 v = *(const float4*)(in + (size_t)k * N + n0 + nc);
    ushort4 u;
    u.x = f2b(v.x); u.y = f2b(v.y); u.z = f2b(v.z); u.w = f2b(v.w);
    *(ushort4*)&s[i * 16 + kr][nc] = u;
  }
  __syncthreads();
  int nl = tid >> 2, kc = tid & 3;
  union { int4 v[2]; u16 u[16]; } o;
#pragma unroll
  for (int j = 0; j < 16; ++j) o.u[j] = s[kc * 16 + j][nl];
  int n = n0 + nl;
  int orow = ((n >> 4) << 5) + half * 16 + (n & 15);
  u16* op = out + (size_t)orow * K + k0 + kc * 16;
  *(int4*)op = o.v[0];
  *(int4*)(op + 8) = o.v[1];
}

// ---------------- Router (fused with x->bf16 conversion) ----------------
// One wave per token. float4 x loads; emits xb bf16 in the same pass. Atomic slot
// assignment to 32x8 padded sub-counters (128B apart) -- R5's contention fix.
__global__ __launch_bounds__(256) void router_kernel(
    const float* __restrict__ x, const float* __restrict__ Wg,
    const float* __restrict__ bg, int* __restrict__ counts32,
    int* __restrict__ tok16, float* __restrict__ g16, u16* __restrict__ xb) {
  int lane = threadIdx.x & 63;
  int t = blockIdx.x * 4 + (threadIdx.x >> 6);
  int sub = blockIdx.x & (NSUB - 1);
  const float* xr = x + (size_t)t * DDIM;
  u16* xo = xb + (size_t)t * DDIM;
  float acc[NEXP];
#pragma unroll
  for (int e = 0; e < NEXP; ++e) acc[e] = 0.f;
#pragma unroll
  for (int jj = 0; jj < DDIM / 256; ++jj) {  // 4 iters, 16B/lane
    int d = jj * 256 + lane * 4;
    float4 xv = *(const float4*)(xr + d);
    ushort4 o;
    o.x = f2b(xv.x); o.y = f2b(xv.y); o.z = f2b(xv.z); o.w = f2b(xv.w);
    *(ushort4*)(xo + d) = o;
    float xs[4] = {xv.x, xv.y, xv.z, xv.w};
#pragma unroll
    for (int dd = 0; dd < 4; ++dd) {
      float4 w0 = *(const float4*)(Wg + (d + dd) * NEXP);
      float4 w1v = *(const float4*)(Wg + (d + dd) * NEXP + 4);
      acc[0] += xs[dd] * w0.x; acc[1] += xs[dd] * w0.y;
      acc[2] += xs[dd] * w0.z; acc[3] += xs[dd] * w0.w;
      acc[4] += xs[dd] * w1v.x; acc[5] += xs[dd] * w1v.y;
      acc[6] += xs[dd] * w1v.z; acc[7] += xs[dd] * w1v.w;
    }
  }
#pragma unroll
  for (int off = 32; off > 0; off >>= 1) {
#pragma unroll
    for (int e = 0; e < NEXP; ++e) acc[e] += __shfl_down(acc[e], off, 64);
  }
  if (lane == 0) {
    float v[NEXP];
#pragma unroll
    for (int e = 0; e < NEXP; ++e) v[e] = acc[e] + bg[e];
    int e0 = 0;
    float v0 = v[0];
#pragma unroll
    for (int e = 1; e < NEXP; ++e)
      if (v[e] > v0) { v0 = v[e]; e0 = e; }  // strict >: lowest index wins ties (jax)
    int e1 = -1;
    float v1 = -3.4e38f;
#pragma unroll
    for (int e = 0; e < NEXP; ++e)
      if (e != e0 && v[e] > v1) { v1 = v[e]; e1 = e; }
    if (e1 < 0) e1 = (e0 + 1) & 7;  // NaN hard-guard
    float ex = __expf(v1 - v0);
    float g0 = 1.f / (1.f + ex);
    float g1 = 1.f - g0;
    int c0 = sub * NEXP + e0;
    int s0 = atomicAdd(&counts32[c0 * CSTRIDE], 1);
    if (s0 < SUBCAP) { tok16[c0 * SUBCAP + s0] = t; g16[c0 * SUBCAP + s0] = g0; }
    int c1 = sub * NEXP + e1;
    int s1 = atomicAdd(&counts32[c1 * CSTRIDE], 1);
    if (s1 < SUBCAP) { tok16[c1 * SUBCAP + s1] = t; g16[c1 * SUBCAP + s1] = g1; }
  }
}

// offsets + per-(e,sub) destination bases + compact worklists (m-tile = 128 rows).
__global__ void offsets_kernel(const int* __restrict__ counts32, int* __restrict__ counts,
                               int* __restrict__ offsets, int* __restrict__ dstbase,
                               int* __restrict__ wl1, int* __restrict__ wl2) {
  int t = threadIdx.x;
  __shared__ int sc[NEXP];
  if (t < NEXP) {
    int c[NSUB];
#pragma unroll
    for (int sub = 0; sub < NSUB; ++sub) c[sub] = counts32[(sub * NEXP + t) * CSTRIDE];
    int run = 0;
#pragma unroll
    for (int sub = 0; sub < NSUB; ++sub) { dstbase[sub * NEXP + t] = run; run += c[sub]; }
    counts[t] = run;
    sc[t] = run;
  }
  __syncthreads();
  if (t == 0) {
    int o = 0;
    for (int e = 0; e < NEXP; ++e) { offsets[e] = o; o += sc[e]; }
    int j1 = 0, j2 = 0;
    for (int e = 0; e < NEXP; ++e) {
      int me = (sc[e] + 127) >> 7;
      for (int m = 0; m < me; ++m) {
        if (j1 + 4 <= WL1_CAP) {
#pragma unroll
          for (int yq = 0; yq < 4; ++yq) wl1[1 + j1 + yq] = (e << 8) | (m << 2) | yq;
          j1 += 4;
        }
        if (j2 < WL2_CAP) wl2[1 + j2++] = (e << 8) | m;
      }
    }
    wl1[0] = j1; wl2[0] = j2;
  }
}

// fold per-(sub,e) scratch into contiguous per-expert tok_ids/gates.
// Also records pos[t][2] = the two global row indices of token t (for combine).
__global__ __launch_bounds__(256) void compact_kernel(
    const int* __restrict__ counts32, const int* __restrict__ dstbase,
    const int* __restrict__ offsets,
    const int* __restrict__ tok16, const float* __restrict__ g16,
    int* __restrict__ tok_ids, float* __restrict__ gates,
    int* __restrict__ posc, int* __restrict__ pos) {
  int idx = blockIdx.x;            // sub*NEXP + e
  int e = idx & (NEXP - 1);
  int n = counts32[idx * CSTRIDE];
  if (n > SUBCAP) n = SUBCAP;
  int base = dstbase[idx];
  int eoff = offsets[e];
  for (int i = threadIdx.x; i < n; i += 256) {
    int t = tok16[idx * SUBCAP + i];
    tok_ids[e * TOKS + base + i] = t;
    gates[e * TOKS + base + i]   = g16[idx * SUBCAP + i];
    int slot = atomicAdd(&posc[t], 1);   // 2 per token, zero contention
    if (slot < 2) pos[t * 2 + slot] = eoff + base + i;
  }
}

// out[t] = y2[pos[t][0]] + y2[pos[t][1]]  (gates already applied in ffn2)
__global__ __launch_bounds__(256) void combine_kernel(
    const float* __restrict__ y2, const int* __restrict__ pos,
    float* __restrict__ out) {
  int t = blockIdx.x;
  int r0 = pos[2 * t], r1 = pos[2 * t + 1];
  int c = threadIdx.x * 4;
  float4 a = *(const float4*)(y2 + (size_t)r0 * DDIM + c);
  float4 b = *(const float4*)(y2 + (size_t)r1 * DDIM + c);
  float4 o;
  o.x = a.x + b.x; o.y = a.y + b.y; o.z = a.z + b.z; o.w = a.w + b.w;
  *(float4*)(out + (size_t)t * DDIM + c) = o;
}

// ---------------- Stage A: h = silu(x@w1)*(x@w3) via ONE GEMM over interleaved wc ----
// R8 structure restored exactly (proven 150us): 128x128 tile, 256 threads,
// single-buffer BK=64, 128B-chunk staging, chunk-XOR swizzle, 64-reg acc, 33KB LDS.
// R10 falsified larger tiles (256x128: 186us clean -- fewer independent barrier
// groups hurt overlap). ONE experiment this round: waves/EU hint 3->4 (cap 128
// regs/wave >= measured 124 = 60 VGPR + 64 AGPR) -> 4 independent blocks/CU.
__global__ __launch_bounds__(256, 4) void ffn1_kernel(
    const u16* __restrict__ xb, const u16* __restrict__ wc,
    const int* __restrict__ tok_ids, const int* __restrict__ counts,
    const int* __restrict__ offsets, const int* __restrict__ wl,
    u16* __restrict__ h, int nbase_wc, int hw, int e_arg) {
  int e, m, y;
  if (e_arg >= 0) {  // Mode B: plain grid, y local to chunk
    e = e_arg; m = blockIdx.x; y = blockIdx.y;
    if (m * 128 >= counts[e]) return;
  } else {           // Mode A: worklist decode
    int bid = blockIdx.x;
    int xcd = bid & 7, j = bid >> 3;
    if (j >= wl[0]) return;
    int w = wl[1 + j];
    e = w >> 8; m = (w >> 2) & 63; y = xcd * 4 + (w & 3);
  }
  int count = counts[e];
  int mbase = m * 128;
  int row_off = (e_arg >= 0) ? 0 : offsets[e];
  int n0w = nbase_wc + y * 128;  // wc-row base of this block
  size_t we = (e_arg >= 0) ? 0 : (size_t)e;
  const u16* wce = wc + we * (size_t)(2 * HDIM * DDIM);

  __shared__ u16 sA[128 * 64];   // 16 KB each
  __shared__ u16 sB[128 * 64];
  __shared__ int stok[128];

  int tid = threadIdx.x, lane = tid & 63, wv = tid >> 6;
  if (tid < 128) {
    int s = mbase + tid;
    if (s >= count) s = count - 1;
    stok[tid] = tok_ids[e * TOKS + s];
  }
  __syncthreads();

  // staging: 32 segments (16 A + 16 B), segment = 8 rows x 128B; 4+4 per wave.
  int rloc = lane >> 3, ch = lane & 7;
  u32 offA[4], offB[4];
#pragma unroll
  for (int i = 0; i < 4; ++i) {
    int r = (wv * 4 + i) * 8 + rloc;     // 0..127
    int sw = ch ^ (r & 7);               // source pre-swizzle
    offA[i] = (u32)stok[r] * DDIM + sw * 8;
    offB[i] = (u32)(n0w + r) * DDIM + sw * 8;
  }

  int wm = wv >> 1, wn = wv & 1;
  int rsel = lane & 15, q = lane >> 4;

  f32x4 acc[4][4];
#pragma unroll
  for (int i = 0; i < 4; ++i)
#pragma unroll
    for (int j = 0; j < 4; ++j) {
      f32x4 z = {0.f, 0.f, 0.f, 0.f};
      acc[i][j] = z;
    }

  for (int k0 = 0; k0 < DDIM; k0 += 64) {
    __syncthreads();  // prior reads done before overwrite
#pragma unroll
    for (int i = 0; i < 4; ++i) {
      int sbase = (wv * 4 + i) * 512;
      glds16(xb  + offA[i] + k0, sA + sbase);
      glds16(wce + offB[i] + k0, sB + sbase);
    }
    __syncthreads();  // staged data visible

#pragma unroll
    for (int ks = 0; ks < 2; ++ks) {
      bf16x8 aF[4], bF[4];
#pragma unroll
      for (int mi = 0; mi < 4; ++mi) {
        int r = wm * 64 + mi * 16 + rsel;
        int p = (ks * 4 + q) ^ (r & 7);
        aF[mi] = *(const bf16x8*)&sA[r * 64 + p * 8];
      }
#pragma unroll
      for (int ni = 0; ni < 4; ++ni) {
        int r = wn * 64 + ni * 16 + rsel;
        int p = (ks * 4 + q) ^ (r & 7);
        bF[ni] = *(const bf16x8*)&sB[r * 64 + p * 8];
      }
#pragma unroll
      for (int mi = 0; mi < 4; ++mi)
#pragma unroll
        for (int ni = 0; ni < 4; ++ni)
          acc[mi][ni] = __builtin_amdgcn_mfma_f32_16x16x32_bf16(aF[mi], bF[ni], acc[mi][ni], 0, 0, 0);
    }
  }

  // epilogue: ni pairs (0,1) and (2,3) are (u,v) for the same 16 h-cols.
  // h col (buffer-local) = y*64 + (wn*2 + np)*16 + rsel.
  int cm = count - mbase;
#pragma unroll
  for (int mi = 0; mi < 4; ++mi) {
#pragma unroll
    for (int rr = 0; rr < 4; ++rr) {
      int mrow = wm * 64 + mi * 16 + q * 4 + rr;  // C/D: row = quad*4+reg
      if (mrow < cm) {
#pragma unroll
        for (int np = 0; np < 2; ++np) {
          int hcol = y * 64 + (wn * 2 + np) * 16 + rsel;
          float u = acc[mi][2 * np][rr];
          float vv = acc[mi][2 * np + 1][rr];
          float hv = (u / (1.f + __expf(-u))) * vv;  // silu(u)*v
          h[(size_t)(row_off + mbase + mrow) * hw + hcol] = f2b(hv);
        }
      }
    }
  }
}

// ---------------- Stage B: y2[row] = gate * (h @ w2t^T)  (or atomic into out) ----
// R8 structure restored exactly. Mode A: y = xcd (w2 panel L2-resident per XCD).
__global__ __launch_bounds__(256) void ffn2_kernel(
    const u16* __restrict__ h, const u16* __restrict__ w2t,
    const int* __restrict__ tok_ids, const float* __restrict__ gates,
    const int* __restrict__ counts, const int* __restrict__ offsets,
    const int* __restrict__ wl, float* __restrict__ out,
    float* __restrict__ y2, int kbase, int hw, int e_arg) {
  int e, m, y;
  if (e_arg >= 0) {
    e = e_arg; m = blockIdx.x; y = blockIdx.y;
    if (m * 128 >= counts[e]) return;
  } else {
    int bid = blockIdx.x;
    int xcd = bid & 7, j = bid >> 3;
    if (j >= wl[0]) return;
    int w = wl[1 + j];
    e = w >> 8; m = w & 63; y = xcd;
  }
  int count = counts[e];
  int mbase = m * 128;
  int row_off = (e_arg >= 0) ? 0 : offsets[e];
  int n0 = y * 128;
  size_t we = (e_arg >= 0) ? 0 : (size_t)e;
  const u16* w2e = w2t + we * (size_t)(HDIM * DDIM);

  __shared__ u16 sA[128 * 64];
  __shared__ u16 sB[128 * 64];
  __shared__ int stok[128];
  __shared__ float sg[128];

  int tid = threadIdx.x, lane = tid & 63, wv = tid >> 6;
  if (tid < 128) {
    int s = mbase + tid;
    if (s >= count) s = count - 1;
    stok[tid] = tok_ids[e * TOKS + s];
    sg[tid] = gates[e * TOKS + s];
  }
  __syncthreads();

  int rloc = lane >> 3, ch = lane & 7;
  u32 offA[4], offB[4];
#pragma unroll
  for (int i = 0; i < 4; ++i) {
    int r = (wv * 4 + i) * 8 + rloc;
    int sw = ch ^ (r & 7);
    int slot = mbase + r;
    if (slot >= count) slot = count - 1;
    offA[i] = (u32)(row_off + slot) * hw + sw * 8;
    offB[i] = (u32)(n0 + r) * HDIM + kbase + sw * 8;
  }

  int wm = wv >> 1, wn = wv & 1;
  int rsel = lane & 15, q = lane >> 4;

  f32x4 acc[4][4];
#pragma unroll
  for (int i = 0; i < 4; ++i)
#pragma unroll
    for (int j = 0; j < 4; ++j) {
      f32x4 z = {0.f, 0.f, 0.f, 0.f};
      acc[i][j] = z;
    }

  for (int k0 = 0; k0 < hw; k0 += 64) {
    __syncthreads();
#pragma unroll
    for (int i = 0; i < 4; ++i) {
      int sbase = (wv * 4 + i) * 512;
      glds16(h   + offA[i] + k0, sA + sbase);
      glds16(w2e + offB[i] + k0, sB + sbase);
    }
    __syncthreads();

#pragma unroll
    for (int ks = 0; ks < 2; ++ks) {
      bf16x8 aF[4], bF[4];
#pragma unroll
      for (int mi = 0; mi < 4; ++mi) {
        int r = wm * 64 + mi * 16 + rsel;
        int p = (ks * 4 + q) ^ (r & 7);
        aF[mi] = *(const bf16x8*)&sA[r * 64 + p * 8];
      }
#pragma unroll
      for (int ni = 0; ni < 4; ++ni) {
        int r = wn * 64 + ni * 16 + rsel;
        int p = (ks * 4 + q) ^ (r & 7);
        bF[ni] = *(const bf16x8*)&sB[r * 64 + p * 8];
      }
#pragma unroll
      for (int mi = 0; mi < 4; ++mi)
#pragma unroll
        for (int ni = 0; ni < 4; ++ni)
          acc[mi][ni] = __builtin_amdgcn_mfma_f32_16x16x32_bf16(aF[mi], bF[ni], acc[mi][ni], 0, 0, 0);
    }
  }

  int cm = count - mbase;
#pragma unroll
  for (int mi = 0; mi < 4; ++mi) {
#pragma unroll
    for (int rr = 0; rr < 4; ++rr) {
      int mrow = wm * 64 + mi * 16 + q * 4 + rr;
      if (mrow < cm) {
        float g = sg[mrow];
        if (y2) {
          size_t rbase = (size_t)(row_off + mbase + mrow) * DDIM;
#pragma unroll
          for (int ni = 0; ni < 4; ++ni) {
            int col = n0 + wn * 64 + ni * 16 + rsel;
            y2[rbase + col] = g * acc[mi][ni][rr];   // private row: plain store
          }
        } else {
          int t = stok[mrow];
#pragma unroll
          for (int ni = 0; ni < 4; ++ni) {
            int col = n0 + wn * 64 + ni * 16 + rsel;
            atomicAdd(&out[(size_t)t * DDIM + col], g * acc[mi][ni][rr]);
          }
        }
      }
    }
  }
}

extern "C" void kernel_launch(void* const* d_in, const int* in_sizes, int n_in,
                              void* d_out, int out_size, void* d_ws, size_t ws_size,
                              hipStream_t stream) {
  (void)in_sizes; (void)n_in; (void)out_size;
  const float* x  = (const float*)d_in[0];
  const float* Wg = (const float*)d_in[1];
  const float* bg = (const float*)d_in[2];
  const float* w1 = (const float*)d_in[3];
  const float* w3 = (const float*)d_in[4];
  const float* w2 = (const float*)d_in[5];
  float* out = (float*)d_out;

  char* ws = (char*)d_ws;
  int*   tok_ids  = (int*)ws;                 // 256 KB
  float* gates    = (float*)(ws + 262144);    // 256 KB
  int*   counts   = (int*)(ws + 524288);      // 64 B
  int*   offsets  = (int*)(ws + 524352);      // 64 B
  int*   wl1      = (int*)(ws + 524416);      // <=4 KB
  int*   wl2      = (int*)(ws + 528512);      // <=1 KB
  int*   dstbase  = (int*)(ws + 529536);      // 1 KB
  int*   counts32 = (int*)(ws + 532480);      // 32 KB (256 counters x 128B)
  int*   posc     = (int*)(ws + 565248);      // 32 KB (adjacent: one 64KB memset)
  int*   tok16    = (int*)(ws + 598016);      // 256 KB
  float* g16      = (float*)(ws + 860160);    // 256 KB
  int*   pos      = (int*)(ws + 1122304);     // 64 KB (TOKS x 2)
  u16*   xb       = (u16*)(ws + (2 << 20));   // 16.78 MB

  const size_t WEXP  = (size_t)HDIM * DDIM * 2;          // 4 MiB per weight per expert
  const size_t WALL  = 3ull * NEXP * WEXP;               // 100.7 MB (wc 64MB + w2t 32MB)
  const size_t HFULL = (size_t)ROWS_TOTAL * HDIM * 2;    // 67.1 MB
  const size_t Y2SZ  = (size_t)ROWS_TOTAL * DDIM * 4;    // 67.1 MB
  const size_t base  = (2 << 20) + 16777216ull;

  hipMemsetAsync(counts32, 0, 65536, stream);  // counts32 + posc (adjacent)

  router_kernel<<<TOKS / 4, 256, 0, stream>>>(x, Wg, bg, counts32, tok16, g16, xb);
  offsets_kernel<<<1, 64, 0, stream>>>(counts32, counts, offsets, dstbase, wl1, wl2);
  compact_kernel<<<NSUB * NEXP, 256, 0, stream>>>(counts32, dstbase, offsets, tok16, g16,
                                                  tok_ids, gates, posc, pos);

  if (ws_size >= base + WALL + HFULL + Y2SZ) {
    // Mode A+: wc (64 MB) + w2t (32 MB) + h (67 MB) + y2 (67 MB); scatter-free ffn2
    u16* wcb = (u16*)(ws + base);                        // [NEXP][2*HDIM][DDIM]
    u16* w2t = wcb + (size_t)NEXP * 2 * HDIM * DDIM;     // [NEXP][DDIM][HDIM]
    u16* hb  = w2t + (size_t)NEXP * HDIM * DDIM;
    float* y2 = (float*)(hb + (size_t)ROWS_TOTAL * HDIM);
    cvt_wc_kernel<<<dim3(HDIM / 64, DDIM / 64, 2 * NEXP), 256, 0, stream>>>(
        w1, w3, wcb, DDIM, HDIM);
    cvt_wT_kernel<<<dim3(DDIM / 64, HDIM / 64, NEXP), 256, 0, stream>>>(w2, w2t, HDIM, DDIM);
    ffn1_kernel<<<dim3(8 * WL1_CAP), 256, 0, stream>>>(
        xb, wcb, tok_ids, counts, offsets, wl1, hb, 0, HDIM, -1);
    ffn2_kernel<<<dim3(8 * WL2_CAP), 256, 0, stream>>>(
        hb, w2t, tok_ids, gates, counts, offsets, wl2, out, y2, 0, HDIM, -1);
    combine_kernel<<<TOKS, 256, 0, stream>>>(y2, pos, out);
  } else if (ws_size >= base + WALL + HFULL) {
    // Mode A: atomic ffn2 (no room for y2)
    u16* wcb = (u16*)(ws + base);
    u16* w2t = wcb + (size_t)NEXP * 2 * HDIM * DDIM;
    u16* hb  = w2t + (size_t)NEXP * HDIM * DDIM;
    hipMemsetAsync(out, 0, (size_t)TOKS * DDIM * 4, stream);
    cvt_wc_kernel<<<dim3(HDIM / 64, DDIM / 64, 2 * NEXP), 256, 0, stream>>>(
        w1, w3, wcb, DDIM, HDIM);
    cvt_wT_kernel<<<dim3(DDIM / 64, HDIM / 64, NEXP), 256, 0, stream>>>(w2, w2t, HDIM, DDIM);
    ffn1_kernel<<<dim3(8 * WL1_CAP), 256, 0, stream>>>(
        xb, wcb, tok_ids, counts, offsets, wl1, hb, 0, HDIM, -1);
    ffn2_kernel<<<dim3(8 * WL2_CAP), 256, 0, stream>>>(
        hb, w2t, tok_ids, gates, counts, offsets, wl2, out, nullptr, 0, HDIM, -1);
  } else {
    // Mode B: per-expert wc (8 MB) + w2t (4 MB) + h chunking; atomic ffn2
    int hw = 128;
    const int cand[5] = {2048, 1024, 512, 256, 128};
    for (int i = 0; i < 5; ++i)
      if (base + 3 * WEXP + (size_t)TOKS * cand[i] * 2 <= ws_size) { hw = cand[i]; break; }
    u16* wcb = (u16*)(ws + base);                        // [2*HDIM][DDIM]
    u16* w2t = wcb + (size_t)2 * HDIM * DDIM;
    u16* hb  = w2t + (size_t)HDIM * DDIM;
    hipMemsetAsync(out, 0, (size_t)TOKS * DDIM * 4, stream);
    for (int e = 0; e < NEXP; ++e) {
      cvt_wc_kernel<<<dim3(HDIM / 64, DDIM / 64, 2), 256, 0, stream>>>(
          w1 + (size_t)e * DDIM * HDIM, w3 + (size_t)e * DDIM * HDIM, wcb, DDIM, HDIM);
      cvt_wT_kernel<<<dim3(DDIM / 64, HDIM / 64, 1), 256, 0, stream>>>(
          w2 + (size_t)e * HDIM * DDIM, w2t, HDIM, DDIM);
      for (int nb = 0; nb < HDIM; nb += hw) {
        // ffn1 over wc rows [2*nb, 2*nb + 2*hw), h chunk cols [nb, nb+hw)
        ffn1_kernel<<<dim3(64, hw / 64, 1), 256, 0, stream>>>(
            xb, wcb, tok_ids, counts, offsets, nullptr, hb, 2 * nb, hw, e);
        ffn2_kernel<<<dim3(64, DDIM / 128, 1), 256, 0, stream>>>(
            hb, w2t, tok_ids, gates, counts, offsets, nullptr, out, nullptr, nb, hw, e);
      }
    }
  }
}